// Round 1
// baseline (4849.564 us; speedup 1.0000x reference)
//
#include <hip/hip_runtime.h>
#include <hip/hip_bf16.h>

// Problem constants
#define B_   4096
#define S_   64
#define D_   9
#define H_   128
#define HZ_  32
#define G4_  512      // 4*H
#define DT_  0.1f

// Workspace layout (float offsets)
#define OFF_WET    0          // 16384  : W_e^T   (256 x 64)
#define OFF_VET    16384      // 4096   : V_e^T   (64 x 64)
#define OFF_WENCT  20480      // 70144  : W_enc^T (137 x 512) rows: [h 0..127 | xs 128..136]
#define OFF_BENC   90624      // 512    : b_ih_enc + b_hh_enc
#define OFF_WDT    91136      // 32768  : W_d^T   (256 x 128)
#define OFF_WDECT  123904     // 135680 : W_dec^T (265 x 512) rows: [d 0..127 | ctx 128..255 | phys 256..264]
#define OFF_BDEC   259584     // 512
#define OFF_WOUTT  260096     // 768    : W_out^T (256 x 3), cat=[d(128) | ctx(128)]
#define OFF_VDT    260864     // 16384  : V_d^T   (128 x 128)
#define OFF_DECD   277248     // 524288 : final encoder h  (decoder d init)
#define OFF_DECC   801536     // 524288 : final encoder c
#define F32_TOTAL  1325824    // floats; bf16 region follows (EH then AE, 33554432 each)
#define PREP_N     277248

#define ENC_M 8
#define DEC_M 8

__device__ __forceinline__ float fast_tanh(float x) {
    // tanh(x) = 1 - 2/(exp(2x)+1); safe at +/-inf
    float e = __expf(2.0f * x);
    return 1.0f - __fdividef(2.0f, e + 1.0f);
}
__device__ __forceinline__ float sigf(float x) {
    return __fdividef(1.0f, 1.0f + __expf(-x));
}
__device__ __forceinline__ float wred_sum(float v) {
    #pragma unroll
    for (int off = 32; off; off >>= 1) v += __shfl_xor(v, off, 64);
    return v;
}

// ---------------------------------------------------------------- prep
__global__ void prep_kernel(const float* __restrict__ Wih_e, const float* __restrict__ Whh_e,
    const float* __restrict__ bih_e, const float* __restrict__ bhh_e,
    const float* __restrict__ W_e, const float* __restrict__ V_e,
    const float* __restrict__ W_d, const float* __restrict__ V_d,
    const float* __restrict__ Wih_d, const float* __restrict__ Whh_d,
    const float* __restrict__ bih_d, const float* __restrict__ bhh_d,
    const float* __restrict__ W_out, float* __restrict__ ws) {
  for (int idx = blockIdx.x * blockDim.x + threadIdx.x; idx < PREP_N;
       idx += gridDim.x * blockDim.x) {
    int i = idx;
    if (i < 16384) { int k = i >> 6, s = i & 63; ws[OFF_WET + i] = W_e[s * 256 + k]; continue; }
    i -= 16384;
    if (i < 4096) { int s = i >> 6, t = i & 63; ws[OFF_VET + i] = V_e[t * 64 + s]; continue; }
    i -= 4096;
    if (i < 70144) {
      int k = i / 512, g = i & 511;
      ws[OFF_WENCT + i] = (k < 128) ? Whh_e[g * 128 + k] : Wih_e[g * 9 + (k - 128)];
      continue;
    }
    i -= 70144;
    if (i < 512) { ws[OFF_BENC + i] = bih_e[i] + bhh_e[i]; continue; }
    i -= 512;
    if (i < 32768) { int k = i >> 7, j = i & 127; ws[OFF_WDT + i] = W_d[j * 256 + k]; continue; }
    i -= 32768;
    if (i < 135680) {
      int k = i / 512, g = i & 511; float v;
      if (k < 128)      v = Whh_d[g * 128 + k];
      else if (k < 256) v = Wih_d[g * 137 + 9 + (k - 128)];
      else              v = Wih_d[g * 137 + (k - 256)];
      ws[OFF_WDECT + i] = v; continue;
    }
    i -= 135680;
    if (i < 512) { ws[OFF_BDEC + i] = bih_d[i] + bhh_d[i]; continue; }
    i -= 512;
    if (i < 768) { int k = i / 3, j = i % 3; ws[OFF_WOUTT + i] = W_out[j * 256 + k]; continue; }
    i -= 768;
    { int ii = i >> 7, j = i & 127; ws[OFF_VDT + i] = V_d[j * 128 + ii]; }
  }
}

// ---------------------------------------------------------------- encoder
__global__ __launch_bounds__(256, 2) void encoder_kernel(
    const float* __restrict__ x_in, const float* __restrict__ ws,
    const float* __restrict__ v_e_g, __hip_bfloat16* __restrict__ EH,
    float* __restrict__ decd, float* __restrict__ decc) {
  __shared__ float hc[ENC_M][272];   // [h 0..127 | c 128..255 | xs 256..264]
  __shared__ float xb[ENC_M][576];   // x[t*9+d]
  __shared__ float ai[ENC_M][576];   // attn_input[d*64+t]
  __shared__ float ah[ENC_M][64];    // attn_hidden
  __shared__ float gl[ENC_M][512];   // gates
  __shared__ float ve[64];

  const int tid = threadIdx.x;
  const int b0 = blockIdx.x * ENC_M;
  const int lane = tid & 63, wv = tid >> 6;

  for (int i = tid; i < ENC_M * 576; i += 256) {
    int m = i / 576, r = i % 576;
    xb[m][r] = x_in[(size_t)(b0 + m) * 576 + r];
  }
  if (tid < 64) ve[tid] = v_e_g[tid];
  for (int i = tid; i < ENC_M * 256; i += 256) { int m = i >> 8, r = i & 255; hc[m][r] = 0.f; }
  __syncthreads();

  // attn_input[m][d][t] = sum_s x[m][s][d] * V_e[t][s]
  const float* __restrict__ VeT = ws + OFF_VET;
  for (int i = tid; i < ENC_M * 576; i += 256) {
    int t = i & 63, dd = (i >> 6) % 9, m = i / 576;
    float acc = 0.f;
    for (int s = 0; s < 64; ++s) acc += xb[m][s * 9 + dd] * VeT[s * 64 + t];
    ai[m][dd * 64 + t] = acc;
  }
  __syncthreads();

  const float* __restrict__ WeT   = ws + OFF_WET;
  const float* __restrict__ WencT = ws + OFF_WENCT;
  const float* __restrict__ benc  = ws + OFF_BENC;

  for (int t = 0; t < S_; ++t) {
    // ---- phase 1: attn_hidden[m][s] = sum_k W_e[s][k]*[h;c][k]
    {
      const int s = lane, m0 = wv, m1 = wv + 4;
      float a0 = 0.f, a1 = 0.f;
      for (int k = 0; k < 256; k += 4) {
        float w0 = WeT[(k + 0) * 64 + s], w1 = WeT[(k + 1) * 64 + s];
        float w2 = WeT[(k + 2) * 64 + s], w3 = WeT[(k + 3) * 64 + s];
        const float4 h0 = *(const float4*)&hc[m0][k];
        const float4 h1 = *(const float4*)&hc[m1][k];
        a0 += w0 * h0.x + w1 * h0.y + w2 * h0.z + w3 * h0.w;
        a1 += w0 * h1.x + w1 * h1.y + w2 * h1.z + w3 * h1.w;
      }
      ah[m0][s] = a0; ah[m1][s] = a1;
    }
    __syncthreads();
    // ---- phase 2: e -> softmax(9) -> xs = alpha * x_t
    #pragma unroll
    for (int half = 0; half < 2; ++half) {
      const int mi = wv + half * 4;
      float e_reg = -1e30f;
      for (int dd = 0; dd < 9; ++dd) {
        float a  = ah[mi][lane] + ai[mi][dd * 64 + lane];
        float tv = fast_tanh(a) * ve[lane];
        float e_dd = wred_sum(tv);
        if (lane == dd) e_reg = e_dd;
      }
      float mval = e_reg;
      #pragma unroll
      for (int off = 8; off; off >>= 1) mval = fmaxf(mval, __shfl_xor(mval, off, 64));
      float ex = (lane < 9) ? __expf(e_reg - mval) : 0.f;
      float ssum = ex;
      #pragma unroll
      for (int off = 8; off; off >>= 1) ssum += __shfl_xor(ssum, off, 64);
      if (lane < 9) hc[mi][256 + lane] = __fdividef(ex, ssum) * xb[mi][t * 9 + lane];
    }
    __syncthreads();
    // ---- phase 3: gates[m][g] = b + W_hh@h + W_ih@xs
    {
      const int g0 = tid, g1 = tid + 256;
      float acc0[ENC_M], acc1[ENC_M];
      const float bb0 = benc[g0], bb1 = benc[g1];
      #pragma unroll
      for (int m = 0; m < ENC_M; ++m) { acc0[m] = bb0; acc1[m] = bb1; }
      for (int k = 0; k < 128; k += 4) {
        float w00 = WencT[(k + 0) * 512 + g0], w01 = WencT[(k + 0) * 512 + g1];
        float w10 = WencT[(k + 1) * 512 + g0], w11 = WencT[(k + 1) * 512 + g1];
        float w20 = WencT[(k + 2) * 512 + g0], w21 = WencT[(k + 2) * 512 + g1];
        float w30 = WencT[(k + 3) * 512 + g0], w31 = WencT[(k + 3) * 512 + g1];
        #pragma unroll
        for (int m = 0; m < ENC_M; ++m) {
          const float4 hv = *(const float4*)&hc[m][k];
          acc0[m] += w00 * hv.x + w10 * hv.y + w20 * hv.z + w30 * hv.w;
          acc1[m] += w01 * hv.x + w11 * hv.y + w21 * hv.z + w31 * hv.w;
        }
      }
      #pragma unroll
      for (int k = 0; k < 9; ++k) {
        float w0 = WencT[(128 + k) * 512 + g0], w1 = WencT[(128 + k) * 512 + g1];
        #pragma unroll
        for (int m = 0; m < ENC_M; ++m) {
          float xv = hc[m][256 + k];
          acc0[m] += w0 * xv; acc1[m] += w1 * xv;
        }
      }
      #pragma unroll
      for (int m = 0; m < ENC_M; ++m) { gl[m][g0] = acc0[m]; gl[m][g1] = acc1[m]; }
    }
    __syncthreads();
    // ---- phase 4: LSTM cell update + store h to EH (bf16)
    #pragma unroll
    for (int q = 0; q < 4; ++q) {
      int flat = tid + q * 256;
      int m = flat >> 7, i = flat & 127;
      float gi = gl[m][i], gf = gl[m][128 + i], gg = gl[m][256 + i], go = gl[m][384 + i];
      float co = hc[m][128 + i];
      float cn = sigf(gf) * co + sigf(gi) * fast_tanh(gg);
      float hn = sigf(go) * fast_tanh(cn);
      hc[m][i] = hn; hc[m][128 + i] = cn;
      EH[((size_t)(b0 + m) * S_ + t) * H_ + i] = __float2bfloat16(hn);
    }
    __syncthreads();
  }
  #pragma unroll
  for (int q = 0; q < 4; ++q) {
    int flat = tid + q * 256;
    int m = flat >> 7, i = flat & 127;
    decd[(size_t)(b0 + m) * H_ + i] = hc[m][i];
    decc[(size_t)(b0 + m) * H_ + i] = hc[m][128 + i];
  }
}

// ---------------------------------------------------------------- attn_encoder = enc_hidden @ V_d^T
__global__ __launch_bounds__(256, 2) void attnenc_kernel(const float* __restrict__ ws,
    const __hip_bfloat16* __restrict__ EH, __hip_bfloat16* __restrict__ AE) {
  __shared__ float rb[16][128];
  const float* __restrict__ VdT = ws + OFF_VDT;
  const int tid = threadIdx.x;
  const int j = tid & 127, half = tid >> 7;
  const size_t r0 = (size_t)blockIdx.x * 256;
  for (int ch = 0; ch < 16; ++ch) {
    __syncthreads();
    for (int e = tid; e < 2048; e += 256) {
      int rr = e >> 7, ii = e & 127;
      rb[rr][ii] = __bfloat162float(EH[(r0 + ch * 16 + rr) * 128 + ii]);
    }
    __syncthreads();
    float acc[8];
    #pragma unroll
    for (int r = 0; r < 8; ++r) acc[r] = 0.f;
    for (int i = 0; i < 128; i += 4) {
      float w0 = VdT[(i + 0) * 128 + j], w1 = VdT[(i + 1) * 128 + j];
      float w2 = VdT[(i + 2) * 128 + j], w3 = VdT[(i + 3) * 128 + j];
      #pragma unroll
      for (int r = 0; r < 8; ++r) {
        const float4 rv = *(const float4*)&rb[half * 8 + r][i];
        acc[r] += w0 * rv.x + w1 * rv.y + w2 * rv.z + w3 * rv.w;
      }
    }
    #pragma unroll
    for (int r = 0; r < 8; ++r)
      AE[(r0 + ch * 16 + half * 8 + r) * 128 + j] = __float2bfloat16(acc[r]);
  }
}

// ---------------------------------------------------------------- decoder
__global__ __launch_bounds__(256, 2) void decoder_kernel(
    const float* __restrict__ x_in, const float* __restrict__ ws,
    const __hip_bfloat16* __restrict__ EH, const __hip_bfloat16* __restrict__ AE,
    const float* __restrict__ v_d_g, const float* __restrict__ b_out_g,
    const float* __restrict__ smean_g, const float* __restrict__ sstd_g,
    const float* __restrict__ pmean_g, float* __restrict__ out) {
  __shared__ float dc[DEC_M][256];     // [d 0..127 | c 128..255]
  __shared__ float ctx[DEC_M][128];
  __shared__ float ad[DEC_M][128];
  __shared__ float phv[DEC_M][12];     // normalized phys (9)
  __shared__ float beta[DEC_M][64];
  __shared__ float gl[DEC_M][512];
  __shared__ float wout[768];
  __shared__ float vd[128];
  __shared__ float partials[192];
  __shared__ float pvs[DEC_M][9];      // pos(0..2) vel(3..5) acc(6..8)
  __shared__ float cons[12];           // smean(0..2) sstd(3..5) pmean(6..8)

  const int tid = threadIdx.x;
  const int b0 = blockIdx.x * DEC_M;
  const int lane = tid & 63, wv = tid >> 6;
  const int j = tid & 127, mb = tid >> 7;

  const float* __restrict__ decd = ws + OFF_DECD;
  const float* __restrict__ decc = ws + OFF_DECC;
  const float* __restrict__ WdT   = ws + OFF_WDT;
  const float* __restrict__ WdecT = ws + OFF_WDECT;
  const float* __restrict__ bdec  = ws + OFF_BDEC;

  #pragma unroll
  for (int q = 0; q < 8; ++q) {
    int flat = tid + q * 256;
    int m = flat >> 8, r = flat & 255;
    dc[m][r] = (r < 128) ? decd[(size_t)(b0 + m) * H_ + r]
                         : decc[(size_t)(b0 + m) * H_ + (r - 128)];
  }
  for (int i = tid; i < 768; i += 256) wout[i] = ws[OFF_WOUTT + i];
  if (tid < 128) vd[tid] = v_d_g[tid];
  if (tid < 3) { cons[tid] = smean_g[tid]; cons[3 + tid] = sstd_g[tid]; cons[6 + tid] = pmean_g[tid]; }
  __syncthreads();
  if (tid < DEC_M * 3) {
    int m = tid / 3, jj = tid % 3;
    const float* xi = x_in + (size_t)(b0 + m) * 576;
    float v  = xi[63 * 9 + 3 + jj] * cons[3 + jj] + cons[jj];
    float pv = xi[62 * 9 + 3 + jj] * cons[3 + jj] + cons[jj];
    pvs[m][jj]     = xi[63 * 9 + jj] + cons[6 + jj];
    pvs[m][3 + jj] = v;
    pvs[m][6 + jj] = (v - pv) / DT_;
  }
  __syncthreads();

  for (int hz = 0; hz < HZ_; ++hz) {
    // ---- a: attn_dec[m][j] = sum_k W_d[j][k]*[d;c][k]
    {
      float a[4] = {0.f, 0.f, 0.f, 0.f};
      for (int k = 0; k < 256; k += 4) {
        float w0 = WdT[(k + 0) * 128 + j], w1 = WdT[(k + 1) * 128 + j];
        float w2 = WdT[(k + 2) * 128 + j], w3 = WdT[(k + 3) * 128 + j];
        #pragma unroll
        for (int q = 0; q < 4; ++q) {
          const float4 hv = *(const float4*)&dc[mb + 2 * q][k];
          a[q] += w0 * hv.x + w1 * hv.y + w2 * hv.z + w3 * hv.w;
        }
      }
      #pragma unroll
      for (int q = 0; q < 4; ++q) ad[mb + 2 * q][j] = a[q];
    }
    __syncthreads();
    // ---- b: scores + softmax over s
    #pragma unroll
    for (int half = 0; half < 2; ++half) {
      const int mi = wv + half * 4;
      const size_t base = ((size_t)(b0 + mi) * S_) * H_;
      float ad0 = ad[mi][lane], ad1 = ad[mi][lane + 64];
      float vd0 = vd[lane],     vd1 = vd[lane + 64];
      float sc_keep = 0.f;
      for (int s = 0; s < 64; ++s) {
        float ae0 = __bfloat162float(AE[base + s * 128 + lane]);
        float ae1 = __bfloat162float(AE[base + s * 128 + lane + 64]);
        float p = fast_tanh(ad0 + ae0) * vd0 + fast_tanh(ad1 + ae1) * vd1;
        float sc = wred_sum(p);
        if (lane == s) sc_keep = sc;
      }
      float mx = sc_keep;
      #pragma unroll
      for (int off = 32; off; off >>= 1) mx = fmaxf(mx, __shfl_xor(mx, off, 64));
      float ex = __expf(sc_keep - mx);
      float ss = ex;
      #pragma unroll
      for (int off = 32; off; off >>= 1) ss += __shfl_xor(ss, off, 64);
      beta[mi][lane] = __fdividef(ex, ss);
    }
    __syncthreads();
    // ---- c: context + phys normalize
    {
      float a[4] = {0.f, 0.f, 0.f, 0.f};
      for (int s = 0; s < 64; ++s) {
        #pragma unroll
        for (int q = 0; q < 4; ++q) {
          int m = mb + 2 * q;
          float e = __bfloat162float(EH[(((size_t)(b0 + m) * S_) + s) * H_ + j]);
          a[q] += beta[m][s] * e;
        }
      }
      #pragma unroll
      for (int q = 0; q < 4; ++q) ctx[mb + 2 * q][j] = a[q];
    }
    if (tid < DEC_M * 3) {
      int m = tid / 3, jj = tid % 3;
      phv[m][jj]     = pvs[m][jj] - cons[6 + jj];
      phv[m][3 + jj] = (pvs[m][3 + jj] - cons[jj]) / cons[3 + jj];
      phv[m][6 + jj] = pvs[m][6 + jj] / cons[3 + jj];
    }
    __syncthreads();
    // ---- d: gates
    {
      const int g0 = tid, g1 = tid + 256;
      float acc0[DEC_M], acc1[DEC_M];
      const float bb0 = bdec[g0], bb1 = bdec[g1];
      #pragma unroll
      for (int m = 0; m < DEC_M; ++m) { acc0[m] = bb0; acc1[m] = bb1; }
      for (int k = 0; k < 128; k += 4) {   // d part
        float w00 = WdecT[(k + 0) * 512 + g0], w01 = WdecT[(k + 0) * 512 + g1];
        float w10 = WdecT[(k + 1) * 512 + g0], w11 = WdecT[(k + 1) * 512 + g1];
        float w20 = WdecT[(k + 2) * 512 + g0], w21 = WdecT[(k + 2) * 512 + g1];
        float w30 = WdecT[(k + 3) * 512 + g0], w31 = WdecT[(k + 3) * 512 + g1];
        #pragma unroll
        for (int m = 0; m < DEC_M; ++m) {
          const float4 hv = *(const float4*)&dc[m][k];
          acc0[m] += w00 * hv.x + w10 * hv.y + w20 * hv.z + w30 * hv.w;
          acc1[m] += w01 * hv.x + w11 * hv.y + w21 * hv.z + w31 * hv.w;
        }
      }
      for (int k = 0; k < 128; k += 4) {   // context part
        float w00 = WdecT[(128 + k + 0) * 512 + g0], w01 = WdecT[(128 + k + 0) * 512 + g1];
        float w10 = WdecT[(128 + k + 1) * 512 + g0], w11 = WdecT[(128 + k + 1) * 512 + g1];
        float w20 = WdecT[(128 + k + 2) * 512 + g0], w21 = WdecT[(128 + k + 2) * 512 + g1];
        float w30 = WdecT[(128 + k + 3) * 512 + g0], w31 = WdecT[(128 + k + 3) * 512 + g1];
        #pragma unroll
        for (int m = 0; m < DEC_M; ++m) {
          const float4 cv = *(const float4*)&ctx[m][k];
          acc0[m] += w00 * cv.x + w10 * cv.y + w20 * cv.z + w30 * cv.w;
          acc1[m] += w01 * cv.x + w11 * cv.y + w21 * cv.z + w31 * cv.w;
        }
      }
      #pragma unroll
      for (int k = 0; k < 9; ++k) {        // phys part
        float w0 = WdecT[(256 + k) * 512 + g0], w1 = WdecT[(256 + k) * 512 + g1];
        #pragma unroll
        for (int m = 0; m < DEC_M; ++m) {
          float xv = phv[m][k];
          acc0[m] += w0 * xv; acc1[m] += w1 * xv;
        }
      }
      #pragma unroll
      for (int m = 0; m < DEC_M; ++m) { gl[m][g0] = acc0[m]; gl[m][g1] = acc1[m]; }
    }
    __syncthreads();
    // ---- e: LSTM cell update
    #pragma unroll
    for (int q = 0; q < 4; ++q) {
      int flat = tid + q * 256;
      int m = flat >> 7, i = flat & 127;
      float gi = gl[m][i], gf = gl[m][128 + i], gg = gl[m][256 + i], go = gl[m][384 + i];
      float co = dc[m][128 + i];
      float cn = sigf(gf) * co + sigf(gi) * fast_tanh(gg);
      float hn = sigf(go) * fast_tanh(cn);
      dc[m][i] = hn; dc[m][128 + i] = cn;
    }
    __syncthreads();
    // ---- f: pred_acc partial dots
    if (tid < 192) {
      int m = tid / 24, jj = (tid % 24) / 8, part = tid % 8;
      int k0 = part * 32;
      float acc = 0.f;
      for (int k = k0; k < k0 + 32; ++k) {
        float v = (k < 128) ? dc[m][k] : ctx[m][k - 128];
        acc += v * wout[k * 3 + jj];
      }
      partials[tid] = acc;
    }
    __syncthreads();
    // ---- g: Verlet update + output
    if (tid < 24) {
      int m = tid / 3, jj = tid % 3;
      float s = b_out_g[jj];
      #pragma unroll
      for (int p = 0; p < 8; ++p) s += partials[m * 24 + jj * 8 + p];
      float pacc = s * cons[3 + jj];
      float pos = pvs[m][jj], vel = pvs[m][3 + jj], acc = pvs[m][6 + jj];
      float ppred = pos + vel * DT_ + 0.5f * acc * DT_ * DT_;
      float vnew  = vel + 0.5f * (acc + pacc) * DT_;
      size_t ob = ((size_t)(b0 + m) * HZ_ + hz) * 9;
      out[ob + jj] = ppred; out[ob + 3 + jj] = vnew; out[ob + 6 + jj] = pacc;
      pvs[m][jj] = ppred; pvs[m][3 + jj] = vnew; pvs[m][6 + jj] = pacc;
    }
    __syncthreads();
  }
}

// ---------------------------------------------------------------- launch
extern "C" void kernel_launch(void* const* d_in, const int* in_sizes, int n_in,
                              void* d_out, int out_size, void* d_ws, size_t ws_size,
                              hipStream_t stream) {
  (void)in_sizes; (void)n_in; (void)out_size; (void)ws_size;
  const float* x      = (const float*)d_in[0];
  const float* Wih_e  = (const float*)d_in[1];
  const float* Whh_e  = (const float*)d_in[2];
  const float* bih_e  = (const float*)d_in[3];
  const float* bhh_e  = (const float*)d_in[4];
  const float* W_e    = (const float*)d_in[5];
  const float* V_e    = (const float*)d_in[6];
  const float* v_e    = (const float*)d_in[7];
  const float* W_d    = (const float*)d_in[8];
  const float* V_d    = (const float*)d_in[9];
  const float* v_d    = (const float*)d_in[10];
  const float* Wih_d  = (const float*)d_in[11];
  const float* Whh_d  = (const float*)d_in[12];
  const float* bih_d  = (const float*)d_in[13];
  const float* bhh_d  = (const float*)d_in[14];
  const float* W_out  = (const float*)d_in[15];
  const float* b_out  = (const float*)d_in[16];
  const float* smean  = (const float*)d_in[17];
  const float* sstd   = (const float*)d_in[18];
  const float* pmean  = (const float*)d_in[19];

  float* ws = (float*)d_ws;
  __hip_bfloat16* EH = (__hip_bfloat16*)(ws + F32_TOTAL);
  __hip_bfloat16* AE = EH + (size_t)B_ * S_ * H_;
  float* out = (float*)d_out;

  prep_kernel<<<(PREP_N + 255) / 256, 256, 0, stream>>>(
      Wih_e, Whh_e, bih_e, bhh_e, W_e, V_e, W_d, V_d,
      Wih_d, Whh_d, bih_d, bhh_d, W_out, ws);
  encoder_kernel<<<B_ / ENC_M, 256, 0, stream>>>(
      x, ws, v_e, EH, ws + OFF_DECD, ws + OFF_DECC);
  attnenc_kernel<<<(B_ * S_) / 256, 256, 0, stream>>>(ws, EH, AE);
  decoder_kernel<<<B_ / DEC_M, 256, 0, stream>>>(
      x, ws, EH, AE, v_d, b_out, smean, sstd, pmean, out);
}